// Round 10
// baseline (344.271 us; speedup 1.0000x reference)
//
#include <hip/hip_runtime.h>

// PatchDecoder round 10: single-variable isolation experiment.
// R8 (weights direct from global, failed @3 blk/CU) with occupancy PINNED
// back to 2 blocks/CU exactly like passing R5: SMem padded to 64KB (3x64KB
// exceeds 160KB -> HW caps at 2 blocks/CU) + __launch_bounds__(256,2).
//   pass -> weights-direct sound; failure was occupancy-3-specific.
//   fail -> weights-direct falsified; R11 reverts to R5-exact.
// All math/schedule is R8 = R5-verbatim (staging deleted; fc0/fc1 read the
// same bytes R5 staged, at the same addresses).

#define TQ 128
#define BLOCK 256
#define HD 128
#define ZD 32
#define NBLK 5
#define GR 64

typedef _Float16 f16x8 __attribute__((ext_vector_type(8)));
typedef _Float16 f16x4 __attribute__((ext_vector_type(4)));
typedef float f32x4 __attribute__((ext_vector_type(4)));

// d_ws layout in halves (VERBATIM R5)
#define OFF_P 0            // fc_p_w [128][32]                  (4096)
#define OFF_C 4096         // fc_c_w [5][128][32]               (20480)
#define OFF_0 24576        // fc0_w  [5][2][64][128] swizzled   (81920)
#define OFF_1 106496       // fc1_w  [5][2][128][64] swizzled   (81920)
#define WS_HALVES 188416

__global__ void convert_weights(const float* __restrict__ fc_p_w,
                                const float* __restrict__ fc_c_w,
                                const float* __restrict__ fc0_w,
                                const float* __restrict__ fc1_w,
                                _Float16* __restrict__ ws) {
  int i = blockIdx.x * 256 + threadIdx.x;
  if (i >= WS_HALVES) return;
  if (i < 4096) {  // Wp linear
    ws[OFF_P + i] = (_Float16)fc_p_w[i];
    return;
  }
  i -= 4096;
  if (i < 20480) {  // Wc linear
    ws[OFF_C + i] = (_Float16)fc_c_w[i];
    return;
  }
  i -= 20480;
  if (i < 81920) {  // W0: [5][2][64][128]; rows contiguous; swizzle cols
    const int row = i >> 7;
    const int col = i & 127;
    const int gs = col >> 3, e = col & 7;
    ws[OFF_0 + i] = (_Float16)fc0_w[(row << 7) + (((gs ^ (row & 7)) << 3) | e)];
    return;
  }
  i -= 81920;
  {  // W1: [5][2 khalf][128 j][64 k] swizzled
    const int c4 = i >> 13;          // layer*2 + khalf
    const int li = c4 >> 1, h = c4 & 1;
    const int r = (i & 8191) >> 6;   // j 0..127
    const int cc = i & 63;
    const int gs = cc >> 3, e = cc & 7;
    const int k = (h << 6) + (((gs ^ (r & 7)) << 3) | e);
    ws[OFF_1 + i] = (_Float16)fc1_w[li * 16384 + (r << 7) + k];
  }
}

struct SMem {
  _Float16 NET[TQ * HD];   // 32KB, relu'd fp16, granule^(q&7); head: gather lat
  _Float16 H[TQ * 64];     // 16KB, relu'd fp16 h-half; tail: epilogue reduce
  _Float16 pad[8192];      // 16KB dead pad: SMem=64KB -> HW caps 2 blocks/CU
};

__device__ __forceinline__ f16x4 relu_pack(const f32x4& a) {
  f16x4 r;
#pragma unroll
  for (int i = 0; i < 4; ++i) r[i] = (_Float16)fmaxf(a[i], 0.f);
  return r;
}

// fc0 half: h[q][0..63] = relu(NET) @ W0chunk^T + b; W frags direct from
// global chunk (16KB, layout identical to R5's staged WB slot).
__device__ __forceinline__ void fc0_half(SMem& sm, const char* __restrict__ w0c,
                                         const float* __restrict__ b0p, int qe,
                                         int lr, int lg) {
  f32x4 hacc[4][2];
#pragma unroll
  for (int jt = 0; jt < 4; ++jt) {
    const f32x4 bv = *(const f32x4*)(b0p + 16 * jt + 4 * lg);
    hacc[jt][0] = bv;
    hacc[jt][1] = bv;
  }
#pragma unroll
  for (int ks = 0; ks < 4; ++ks) {
    f16x8 af[4];
#pragma unroll
    for (int jt = 0; jt < 4; ++jt)
      af[jt] = *(const f16x8*)(w0c + (16 * jt + lr) * 256 +
                               (((4 * ks + lg) ^ (lr & 7)) << 4));
    f16x8 xf[2];
#pragma unroll
    for (int q2 = 0; q2 < 2; ++q2) {
      const int q = qe + 16 * q2 + lr;
      xf[q2] = *(const f16x8*)((const char*)sm.NET + q * 256 +
                               (((4 * ks + lg) ^ (q & 7)) << 4));
    }
#pragma unroll
    for (int jt = 0; jt < 4; ++jt)
#pragma unroll
      for (int q2 = 0; q2 < 2; ++q2)
        hacc[jt][q2] = __builtin_amdgcn_mfma_f32_16x16x32_f16(af[jt], xf[q2],
                                                              hacc[jt][q2], 0, 0, 0);
  }
#pragma unroll
  for (int jt = 0; jt < 4; ++jt)
#pragma unroll
    for (int q2 = 0; q2 < 2; ++q2) {
      const int q = qe + 16 * q2 + lr;
      const int G = (2 * jt + (lg >> 1)) ^ (q & 7);
      *(f16x4*)((char*)sm.H + q * 128 + (G << 4) + ((lg & 1) << 3)) =
          relu_pack(hacc[jt][q2]);
    }
}

// fc1 half: acc += H @ W1chunk^T (k-partial); W frags direct from global chunk.
__device__ __forceinline__ void fc1_half(SMem& sm, const char* __restrict__ w1c,
                                         f32x4 (&acc)[4][4], int j0, int q0,
                                         int lr, int lg) {
#pragma unroll
  for (int ks = 0; ks < 2; ++ks) {
    f16x8 a1[4];
#pragma unroll
    for (int jt = 0; jt < 4; ++jt)
      a1[jt] = *(const f16x8*)(w1c + (j0 + 16 * jt + lr) * 128 +
                               (((4 * ks + lg) ^ (lr & 7)) << 4));
    f16x8 hf[4];
#pragma unroll
    for (int qt = 0; qt < 4; ++qt) {
      const int q = q0 + 16 * qt + lr;
      hf[qt] = *(const f16x8*)((const char*)sm.H + q * 128 +
                               (((4 * ks + lg) ^ (q & 7)) << 4));
    }
#pragma unroll
    for (int jt = 0; jt < 4; ++jt)
#pragma unroll
      for (int qt = 0; qt < 4; ++qt)
        acc[jt][qt] = __builtin_amdgcn_mfma_f32_16x16x32_f16(a1[jt], hf[qt],
                                                             acc[jt][qt], 0, 0, 0);
  }
}

__global__ __launch_bounds__(BLOCK, 2) void patch_decoder_kernel(
    const float* __restrict__ z_feats, const float* __restrict__ query,
    const _Float16* __restrict__ ws, const float* __restrict__ fc_p_b,
    const float* __restrict__ fc_c_b, const float* __restrict__ fc0_b,
    const float* __restrict__ fc1_b, const float* __restrict__ fc_out_w,
    const float* __restrict__ fc_out_b, float* __restrict__ out, int nq) {
  __shared__ SMem sm;
  const int t = threadIdx.x;
  const int w = t >> 6;
  const int l = t & 63;
  const int lr = l & 15, lg = l >> 4;
  const int j0 = (w & 1) << 6;     // main partition: j-half
  const int q0 = (w >> 1) << 6;    // main partition: q-half (64 q)
  const int qe = w << 5;           // fc0 phases: q-quarter (32 q)
  const int qbase = blockIdx.x * TQ;

  const char* w0base = (const char*)(ws + OFF_0);
  const char* w1base = (const char*)(ws + OFF_1);

  // ---- gather: 2 threads/query, 16 feats each; lat -> NET head (80B rows) ----
  {
    const int q = t >> 1, s = t & 1;
    const int qg = qbase + q;
    float acc[16];
#pragma unroll
    for (int e = 0; e < 16; ++e) acc[e] = 0.f;
    if (qg < nq) {
      const float qx = query[qg * 3 + 0];
      const float qy = query[qg * 3 + 1];
      const float qz = query[qg * 3 + 2];
      const float fx = floorf(qx), fy = floorf(qy), fz = floorf(qz);
      const float rx = qx - fx, ry = qy - fy, rz = qz - fz;
      const int bx = (int)fx, by = (int)fy, bz = (int)fz;
      const float wx[2] = {1.f - rx, rx}, wy[2] = {1.f - ry, ry},
                  wz[2] = {1.f - rz, rz};
#pragma unroll
      for (int c = 0; c < 8; ++c) {
        const int ox = (c >> 2) & 1, oy = (c >> 1) & 1, oz = c & 1;
        const float wgt = wx[ox] * wy[oy] * wz[oz];
        const float* f = z_feats +
                         (size_t)(((bx + ox) * GR + (by + oy)) * GR + (bz + oz)) * ZD +
                         s * 16;
#pragma unroll
        for (int v4 = 0; v4 < 4; ++v4) {
          const float4 v = *(const float4*)(f + v4 * 4);
          acc[v4 * 4 + 0] = fmaf(wgt, v.x, acc[v4 * 4 + 0]);
          acc[v4 * 4 + 1] = fmaf(wgt, v.y, acc[v4 * 4 + 1]);
          acc[v4 * 4 + 2] = fmaf(wgt, v.z, acc[v4 * 4 + 2]);
          acc[v4 * 4 + 3] = fmaf(wgt, v.w, acc[v4 * 4 + 3]);
        }
      }
    }
    f16x8 h0, h1;
#pragma unroll
    for (int e = 0; e < 8; ++e) {
      h0[e] = (_Float16)acc[e];
      h1[e] = (_Float16)acc[8 + e];
    }
    char* lb = (char*)sm.NET + q * 80 + s * 32;
    *(f16x8*)lb = h0;
    *(f16x8*)(lb + 16) = h1;
  }
  __syncthreads();  // bar0: lat visible

  // ---- latf (persist) ----
  f16x8 latf[4];
#pragma unroll
  for (int qt = 0; qt < 4; ++qt)
    latf[qt] =
        *(const f16x8*)((const char*)sm.NET + (q0 + 16 * qt + lr) * 80 + lg * 16);
  __syncthreads();  // all lat reads retired before P0 rewrites NET

  // ---- fc_p ----
  f32x4 acc[4][4];
#pragma unroll
  for (int jt = 0; jt < 4; ++jt) {
    const f32x4 bv = *(const f32x4*)(fc_p_b + j0 + 16 * jt + 4 * lg);
#pragma unroll
    for (int qt = 0; qt < 4; ++qt) acc[jt][qt] = bv;
  }
#pragma unroll
  for (int jt = 0; jt < 4; ++jt) {
    const f16x8 wf = *(const f16x8*)(ws + OFF_P + (j0 + 16 * jt + lr) * 32 + lg * 8);
#pragma unroll
    for (int qt = 0; qt < 4; ++qt)
      acc[jt][qt] = __builtin_amdgcn_mfma_f32_16x16x32_f16(wf, latf[qt], acc[jt][qt],
                                                           0, 0, 0);
  }

#pragma unroll 1
  for (int i = 0; i < NBLK; ++i) {
    // ---- P0: fc_c (direct-global frags) + bias; write relu(net) -> NET ----
#pragma unroll
    for (int jt = 0; jt < 4; ++jt) {
      const f16x8 wf =
          *(const f16x8*)(ws + OFF_C + i * 4096 + (j0 + 16 * jt + lr) * 32 + lg * 8);
#pragma unroll
      for (int qt = 0; qt < 4; ++qt)
        acc[jt][qt] = __builtin_amdgcn_mfma_f32_16x16x32_f16(wf, latf[qt],
                                                             acc[jt][qt], 0, 0, 0);
      const f32x4 bv = *(const f32x4*)(fc_c_b + i * HD + j0 + 16 * jt + 4 * lg);
#pragma unroll
      for (int qt = 0; qt < 4; ++qt) acc[jt][qt] += bv;
    }
#pragma unroll
    for (int jt = 0; jt < 4; ++jt)
#pragma unroll
      for (int qt = 0; qt < 4; ++qt) {
        const int q = q0 + 16 * qt + lr;
        const int G = ((j0 >> 3) + 2 * jt + (lg >> 1)) ^ (q & 7);
        *(f16x4*)((char*)sm.NET + q * 256 + (G << 4) + ((lg & 1) << 3)) =
            relu_pack(acc[jt][qt]);
      }
    __syncthreads();  // bar1: NET ready; prev-iter P4 H-readers done

    // ---- P1: h0 = relu(NET) @ W0h0 (global chunk) -> H ----
    fc0_half(sm, w0base + i * 32768, fc0_b + i * HD, qe, lr, lg);
    __syncthreads();  // bar2: H(k0) ready

    // ---- P2: dx += H @ W1k0 (global chunk) ----
    fc1_half(sm, w1base + i * 32768, acc, j0, q0, lr, lg);
    __syncthreads();  // bar3: H(k0) reads done

    // ---- P3: h1 = relu(NET) @ W0h1 (global chunk) -> H ----
    fc0_half(sm, w0base + i * 32768 + 16384, fc0_b + i * HD + 64, qe, lr, lg);
    __syncthreads();  // bar4: H(k1) ready; NET readers done

    // ---- P4: dx += H @ W1k1 (global chunk) ; net += b1 ----
    fc1_half(sm, w1base + i * 32768 + 16384, acc, j0, q0, lr, lg);
#pragma unroll
    for (int jt = 0; jt < 4; ++jt) {
      const f32x4 bv = *(const f32x4*)(fc1_b + i * HD + j0 + 16 * jt + 4 * lg);
#pragma unroll
      for (int qt = 0; qt < 4; ++qt) acc[jt][qt] += bv;
    }
    // no barrier: P0(i+1) writes NET, whose last readers (P3) retired at bar4
  }
  __syncthreads();  // final: H readers (P4) done; H reusable as reduce scratch

  // ---- epilogue: out[q] = leaky(net) . wout + b ----
  float* red = (float*)sm.H;  // [2][128] f32 partials
  {
    float p[4];
#pragma unroll
    for (int qt = 0; qt < 4; ++qt) p[qt] = 0.f;
#pragma unroll
    for (int jt = 0; jt < 4; ++jt) {
      const f32x4 wv = *(const f32x4*)(fc_out_w + j0 + 16 * jt + 4 * lg);
#pragma unroll
      for (int qt = 0; qt < 4; ++qt) {
        const f32x4 a = acc[jt][qt];
#pragma unroll
        for (int r = 0; r < 4; ++r) {
          const float v = (a[r] > 0.f) ? a[r] : 0.2f * a[r];
          p[qt] = fmaf(v, wv[r], p[qt]);
        }
      }
    }
#pragma unroll
    for (int qt = 0; qt < 4; ++qt) {
      p[qt] += __shfl_xor(p[qt], 16);
      p[qt] += __shfl_xor(p[qt], 32);
    }
    if (lg == 0) {
#pragma unroll
      for (int qt = 0; qt < 4; ++qt)
        red[(w & 1) * TQ + q0 + 16 * qt + lr] = p[qt];
    }
  }
  __syncthreads();
  if (t < TQ) {
    const int qg = qbase + t;
    if (qg < nq) out[qg] = red[t] + red[TQ + t] + fc_out_b[0];
  }
}

extern "C" void kernel_launch(void* const* d_in, const int* in_sizes, int n_in,
                              void* d_out, int out_size, void* d_ws,
                              size_t ws_size, hipStream_t stream) {
  const float* z_feats = (const float*)d_in[0];
  const float* query = (const float*)d_in[1];
  const float* fc_p_w = (const float*)d_in[2];
  const float* fc_p_b = (const float*)d_in[3];
  const float* fc_c_w = (const float*)d_in[4];
  const float* fc_c_b = (const float*)d_in[5];
  const float* fc0_w = (const float*)d_in[6];
  const float* fc0_b = (const float*)d_in[7];
  const float* fc1_w = (const float*)d_in[8];
  const float* fc1_b = (const float*)d_in[9];
  const float* fc_out_w = (const float*)d_in[10];
  const float* fc_out_b = (const float*)d_in[11];
  float* out = (float*)d_out;
  _Float16* ws = (_Float16*)d_ws;

  const int nq = in_sizes[1] / 3;

  convert_weights<<<(WS_HALVES + 255) / 256, 256, 0, stream>>>(fc_p_w, fc_c_w,
                                                               fc0_w, fc1_w, ws);
  const int grid = (nq + TQ - 1) / TQ;
  patch_decoder_kernel<<<grid, BLOCK, 0, stream>>>(z_feats, query, ws, fc_p_b,
                                                   fc_c_b, fc0_b, fc1_b, fc_out_w,
                                                   fc_out_b, out, nq);
}

// Round 11
// 298.341 us; speedup vs baseline: 1.1540x; 1.1540x over previous
//
#include <hip/hip_runtime.h>

// PatchDecoder round 11: hybrid of proven parts.
// Base = R5 (passing, 277us, 2 blk/CU): TQ=128, 4 waves, W0 LDS-staged via
// global_load_lds, 5-phase/4-barrier schedule.
// Deltas (each independently de-risked):
//  1. W1 frags read DIRECT from global (R10's exact reads, proven @occ2):
//     removes 16 b128 LDS reads/wave/iter (~20% of LDS read traffic) and both
//     B-slot stages; fc1's 8 global loads have no LDS dependency -> issue at
//     phase start, L2 latency hides under hf ds_reads + MFMA.
//  2. Defensive barrier after latf loads (R10) -> closes R5's latent lat race.
//  3. s_setprio(1) around MFMA clusters (T5): 2 independent blocks/CU give
//     cross-block phase diversity to arbitrate.
// LDS: NET 32KB + H 16KB + 1 slot 16KB = 64KB -> 2 blocks/CU.

#define TQ 128
#define BLOCK 256
#define HD 128
#define ZD 32
#define NBLK 5
#define GR 64

typedef _Float16 f16x8 __attribute__((ext_vector_type(8)));
typedef _Float16 f16x4 __attribute__((ext_vector_type(4)));
typedef float f32x4 __attribute__((ext_vector_type(4)));

// d_ws layout in halves (VERBATIM R5)
#define OFF_P 0            // fc_p_w [128][32]                  (4096)
#define OFF_C 4096         // fc_c_w [5][128][32]               (20480)
#define OFF_0 24576        // fc0_w  [5][2][64][128] swizzled   (81920)
#define OFF_1 106496       // fc1_w  [5][2][128][64] swizzled   (81920)
#define WS_HALVES 188416

__global__ void convert_weights(const float* __restrict__ fc_p_w,
                                const float* __restrict__ fc_c_w,
                                const float* __restrict__ fc0_w,
                                const float* __restrict__ fc1_w,
                                _Float16* __restrict__ ws) {
  int i = blockIdx.x * 256 + threadIdx.x;
  if (i >= WS_HALVES) return;
  if (i < 4096) {  // Wp linear
    ws[OFF_P + i] = (_Float16)fc_p_w[i];
    return;
  }
  i -= 4096;
  if (i < 20480) {  // Wc linear
    ws[OFF_C + i] = (_Float16)fc_c_w[i];
    return;
  }
  i -= 20480;
  if (i < 81920) {  // W0: [5][2][64][128]; rows contiguous; swizzle cols
    const int row = i >> 7;
    const int col = i & 127;
    const int gs = col >> 3, e = col & 7;
    ws[OFF_0 + i] = (_Float16)fc0_w[(row << 7) + (((gs ^ (row & 7)) << 3) | e)];
    return;
  }
  i -= 81920;
  {  // W1: [5][2 khalf][128 j][64 k] swizzled
    const int c4 = i >> 13;          // layer*2 + khalf
    const int li = c4 >> 1, h = c4 & 1;
    const int r = (i & 8191) >> 6;   // j 0..127
    const int cc = i & 63;
    const int gs = cc >> 3, e = cc & 7;
    const int k = (h << 6) + (((gs ^ (r & 7)) << 3) | e);
    ws[OFF_1 + i] = (_Float16)fc1_w[li * 16384 + (r << 7) + k];
  }
}

struct SMem {
  _Float16 NET[TQ * HD];   // 32KB, relu'd fp16, granule^(q&7); head: gather lat
  _Float16 H[TQ * 64];     // 16KB, relu'd fp16 h-half; tail: epilogue reduce
  _Float16 WA[8192];       // 16KB slot: W0h0 -> W0h1 -> W0h0(i+1)
};

// async stage one 16KB chunk: 256 threads x 16B x 4 issues, LDS-linear
__device__ __forceinline__ void stage_chunk(char* lds, const char* g, int t) {
#pragma unroll
  for (int r = 0; r < 4; ++r) {
    __builtin_amdgcn_global_load_lds(
        (const __attribute__((address_space(1))) void*)(g + r * 4096 + t * 16),
        (__attribute__((address_space(3))) void*)(lds + r * 4096 + t * 16), 16,
        0, 0);
  }
}

__device__ __forceinline__ f16x4 relu_pack(const f32x4& a) {
  f16x4 r;
#pragma unroll
  for (int i = 0; i < 4; ++i) r[i] = (_Float16)fmaxf(a[i], 0.f);
  return r;
}

// fc0 half: h[q][0..63] = relu(NET) @ W0chunk^T + b; W0 from LDS slot WA
__device__ __forceinline__ void fc0_half(SMem& sm,
                                         const float* __restrict__ b0p, int qe,
                                         int lr, int lg) {
  f32x4 hacc[4][2];
#pragma unroll
  for (int jt = 0; jt < 4; ++jt) {
    const f32x4 bv = *(const f32x4*)(b0p + 16 * jt + 4 * lg);
    hacc[jt][0] = bv;
    hacc[jt][1] = bv;
  }
#pragma unroll
  for (int ks = 0; ks < 4; ++ks) {
    f16x8 af[4];
#pragma unroll
    for (int jt = 0; jt < 4; ++jt)
      af[jt] = *(const f16x8*)((const char*)sm.WA + (16 * jt + lr) * 256 +
                               (((4 * ks + lg) ^ (lr & 7)) << 4));
    f16x8 xf[2];
#pragma unroll
    for (int q2 = 0; q2 < 2; ++q2) {
      const int q = qe + 16 * q2 + lr;
      xf[q2] = *(const f16x8*)((const char*)sm.NET + q * 256 +
                               (((4 * ks + lg) ^ (q & 7)) << 4));
    }
    __builtin_amdgcn_s_setprio(1);
#pragma unroll
    for (int jt = 0; jt < 4; ++jt)
#pragma unroll
      for (int q2 = 0; q2 < 2; ++q2)
        hacc[jt][q2] = __builtin_amdgcn_mfma_f32_16x16x32_f16(af[jt], xf[q2],
                                                              hacc[jt][q2], 0, 0, 0);
    __builtin_amdgcn_s_setprio(0);
  }
#pragma unroll
  for (int jt = 0; jt < 4; ++jt)
#pragma unroll
    for (int q2 = 0; q2 < 2; ++q2) {
      const int q = qe + 16 * q2 + lr;
      const int G = (2 * jt + (lg >> 1)) ^ (q & 7);
      *(f16x4*)((char*)sm.H + q * 128 + (G << 4) + ((lg & 1) << 3)) =
          relu_pack(hacc[jt][q2]);
    }
}

// fc1 half: acc += H @ W1chunk^T (k-partial); W1 frags DIRECT from global
// chunk (16KB region, byte-identical layout to R5's staged slot; proven R10).
__device__ __forceinline__ void fc1_half(SMem& sm, const char* __restrict__ w1c,
                                         f32x4 (&acc)[4][4], int j0, int q0,
                                         int lr, int lg) {
  // issue all 8 W1 global loads up front (no LDS dependency -> L2 latency
  // hides under the hf ds_reads + MFMA chain)
  f16x8 a1[2][4];
#pragma unroll
  for (int ks = 0; ks < 2; ++ks)
#pragma unroll
    for (int jt = 0; jt < 4; ++jt)
      a1[ks][jt] = *(const f16x8*)(w1c + (j0 + 16 * jt + lr) * 128 +
                                   (((4 * ks + lg) ^ (lr & 7)) << 4));
#pragma unroll
  for (int ks = 0; ks < 2; ++ks) {
    f16x8 hf[4];
#pragma unroll
    for (int qt = 0; qt < 4; ++qt) {
      const int q = q0 + 16 * qt + lr;
      hf[qt] = *(const f16x8*)((const char*)sm.H + q * 128 +
                               (((4 * ks + lg) ^ (q & 7)) << 4));
    }
    __builtin_amdgcn_s_setprio(1);
#pragma unroll
    for (int jt = 0; jt < 4; ++jt)
#pragma unroll
      for (int qt = 0; qt < 4; ++qt)
        acc[jt][qt] = __builtin_amdgcn_mfma_f32_16x16x32_f16(a1[ks][jt], hf[qt],
                                                             acc[jt][qt], 0, 0, 0);
    __builtin_amdgcn_s_setprio(0);
  }
}

__global__ __launch_bounds__(BLOCK, 2) void patch_decoder_kernel(
    const float* __restrict__ z_feats, const float* __restrict__ query,
    const _Float16* __restrict__ ws, const float* __restrict__ fc_p_b,
    const float* __restrict__ fc_c_b, const float* __restrict__ fc0_b,
    const float* __restrict__ fc1_b, const float* __restrict__ fc_out_w,
    const float* __restrict__ fc_out_b, float* __restrict__ out, int nq) {
  __shared__ SMem sm;
  const int t = threadIdx.x;
  const int w = t >> 6;
  const int l = t & 63;
  const int lr = l & 15, lg = l >> 4;
  const int j0 = (w & 1) << 6;     // main partition: j-half
  const int q0 = (w >> 1) << 6;    // main partition: q-half (64 q)
  const int qe = w << 5;           // fc0 phases: q-quarter (32 q)
  const int qbase = blockIdx.x * TQ;

  const char* w0base = (const char*)(ws + OFF_0);
  const char* w1base = (const char*)(ws + OFF_1);

  // ---- prologue: async-stage iter-0 W0h0 (lands during gather) ----
  stage_chunk((char*)sm.WA, w0base, t);

  // ---- gather: 2 threads/query, 16 feats each; lat -> NET head (80B rows) ----
  {
    const int q = t >> 1, s = t & 1;
    const int qg = qbase + q;
    float acc[16];
#pragma unroll
    for (int e = 0; e < 16; ++e) acc[e] = 0.f;
    if (qg < nq) {
      const float qx = query[qg * 3 + 0];
      const float qy = query[qg * 3 + 1];
      const float qz = query[qg * 3 + 2];
      const float fx = floorf(qx), fy = floorf(qy), fz = floorf(qz);
      const float rx = qx - fx, ry = qy - fy, rz = qz - fz;
      const int bx = (int)fx, by = (int)fy, bz = (int)fz;
      const float wx[2] = {1.f - rx, rx}, wy[2] = {1.f - ry, ry},
                  wz[2] = {1.f - rz, rz};
#pragma unroll
      for (int c = 0; c < 8; ++c) {
        const int ox = (c >> 2) & 1, oy = (c >> 1) & 1, oz = c & 1;
        const float wgt = wx[ox] * wy[oy] * wz[oz];
        const float* f = z_feats +
                         (size_t)(((bx + ox) * GR + (by + oy)) * GR + (bz + oz)) * ZD +
                         s * 16;
#pragma unroll
        for (int v4 = 0; v4 < 4; ++v4) {
          const float4 v = *(const float4*)(f + v4 * 4);
          acc[v4 * 4 + 0] = fmaf(wgt, v.x, acc[v4 * 4 + 0]);
          acc[v4 * 4 + 1] = fmaf(wgt, v.y, acc[v4 * 4 + 1]);
          acc[v4 * 4 + 2] = fmaf(wgt, v.z, acc[v4 * 4 + 2]);
          acc[v4 * 4 + 3] = fmaf(wgt, v.w, acc[v4 * 4 + 3]);
        }
      }
    }
    f16x8 h0, h1;
#pragma unroll
    for (int e = 0; e < 8; ++e) {
      h0[e] = (_Float16)acc[e];
      h1[e] = (_Float16)acc[8 + e];
    }
    char* lb = (char*)sm.NET + q * 80 + s * 32;
    *(f16x8*)lb = h0;
    *(f16x8*)(lb + 16) = h1;
  }
  __syncthreads();  // bar0: lat visible; prologue chunk drained

  // ---- latf (persist) ----
  f16x8 latf[4];
#pragma unroll
  for (int qt = 0; qt < 4; ++qt)
    latf[qt] =
        *(const f16x8*)((const char*)sm.NET + (q0 + 16 * qt + lr) * 80 + lg * 16);
  __syncthreads();  // all lat reads retired before P0 rewrites NET (R10-proven)

  // ---- fc_p ----
  f32x4 acc[4][4];
#pragma unroll
  for (int jt = 0; jt < 4; ++jt) {
    const f32x4 bv = *(const f32x4*)(fc_p_b + j0 + 16 * jt + 4 * lg);
#pragma unroll
    for (int qt = 0; qt < 4; ++qt) acc[jt][qt] = bv;
  }
#pragma unroll
  for (int jt = 0; jt < 4; ++jt) {
    const f16x8 wf = *(const f16x8*)(ws + OFF_P + (j0 + 16 * jt + lr) * 32 + lg * 8);
#pragma unroll
    for (int qt = 0; qt < 4; ++qt)
      acc[jt][qt] = __builtin_amdgcn_mfma_f32_16x16x32_f16(wf, latf[qt], acc[jt][qt],
                                                           0, 0, 0);
  }

#pragma unroll 1
  for (int i = 0; i < NBLK; ++i) {
    // ---- P0: fc_c (direct-global frags) + bias; write relu(net) -> NET ----
#pragma unroll
    for (int jt = 0; jt < 4; ++jt) {
      const f16x8 wf =
          *(const f16x8*)(ws + OFF_C + i * 4096 + (j0 + 16 * jt + lr) * 32 + lg * 8);
      __builtin_amdgcn_s_setprio(1);
#pragma unroll
      for (int qt = 0; qt < 4; ++qt)
        acc[jt][qt] = __builtin_amdgcn_mfma_f32_16x16x32_f16(wf, latf[qt],
                                                             acc[jt][qt], 0, 0, 0);
      __builtin_amdgcn_s_setprio(0);
      const f32x4 bv = *(const f32x4*)(fc_c_b + i * HD + j0 + 16 * jt + 4 * lg);
#pragma unroll
      for (int qt = 0; qt < 4; ++qt) acc[jt][qt] += bv;
    }
#pragma unroll
    for (int jt = 0; jt < 4; ++jt)
#pragma unroll
      for (int qt = 0; qt < 4; ++qt) {
        const int q = q0 + 16 * qt + lr;
        const int G = ((j0 >> 3) + 2 * jt + (lg >> 1)) ^ (q & 7);
        *(f16x4*)((char*)sm.NET + q * 256 + (G << 4) + ((lg & 1) << 3)) =
            relu_pack(acc[jt][qt]);
      }
    __syncthreads();  // bar1: NET ready; prev-iter P4 H-readers done

    // ---- P1: h0 = relu(NET) @ W0h0 (slot WA) -> H ----
    fc0_half(sm, fc0_b + i * HD, qe, lr, lg);
    __syncthreads();  // bar2: H(k0) ready; WA readers done

    stage_chunk((char*)sm.WA, w0base + i * 32768 + 16384, t);  // WA<-W0h1(i)
    // ---- P2: dx += H @ W1k0 (W1 direct from global) ----
    fc1_half(sm, w1base + i * 32768, acc, j0, q0, lr, lg);
    __syncthreads();  // bar3: H(k0) reads done; WA(W0h1) drained

    // ---- P3: h1 = relu(NET) @ W0h1 (slot WA) -> H ----
    fc0_half(sm, fc0_b + i * HD + 64, qe, lr, lg);
    __syncthreads();  // bar4: H(k1) ready; WA readers + NET readers done

    if (i + 1 < NBLK)
      stage_chunk((char*)sm.WA, w0base + (i + 1) * 32768, t);  // WA<-W0h0(i+1)
    // ---- P4: dx += H @ W1k1 (direct) ; net += b1 ----
    fc1_half(sm, w1base + i * 32768 + 16384, acc, j0, q0, lr, lg);
#pragma unroll
    for (int jt = 0; jt < 4; ++jt) {
      const f32x4 bv = *(const f32x4*)(fc1_b + i * HD + j0 + 16 * jt + 4 * lg);
#pragma unroll
      for (int qt = 0; qt < 4; ++qt) acc[jt][qt] += bv;
    }
    // no barrier: P0(i+1) writes NET, whose last readers (P3) retired at bar4
  }
  __syncthreads();  // final: H readers (P4) done; H reusable as reduce scratch

  // ---- epilogue: out[q] = leaky(net) . wout + b ----
  float* red = (float*)sm.H;  // [2][128] f32 partials
  {
    float p[4];
#pragma unroll
    for (int qt = 0; qt < 4; ++qt) p[qt] = 0.f;
#pragma unroll
    for (int jt = 0; jt < 4; ++jt) {
      const f32x4 wv = *(const f32x4*)(fc_out_w + j0 + 16 * jt + 4 * lg);
#pragma unroll
      for (int qt = 0; qt < 4; ++qt) {
        const f32x4 a = acc[jt][qt];
#pragma unroll
        for (int r = 0; r < 4; ++r) {
          const float v = (a[r] > 0.f) ? a[r] : 0.2f * a[r];
          p[qt] = fmaf(v, wv[r], p[qt]);
        }
      }
    }
#pragma unroll
    for (int qt = 0; qt < 4; ++qt) {
      p[qt] += __shfl_xor(p[qt], 16);
      p[qt] += __shfl_xor(p[qt], 32);
    }
    if (lg == 0) {
#pragma unroll
      for (int qt = 0; qt < 4; ++qt)
        red[(w & 1) * TQ + q0 + 16 * qt + lr] = p[qt];
    }
  }
  __syncthreads();
  if (t < TQ) {
    const int qg = qbase + t;
    if (qg < nq) out[qg] = red[t] + red[TQ + t] + fc_out_b[0];
  }
}

extern "C" void kernel_launch(void* const* d_in, const int* in_sizes, int n_in,
                              void* d_out, int out_size, void* d_ws,
                              size_t ws_size, hipStream_t stream) {
  const float* z_feats = (const float*)d_in[0];
  const float* query = (const float*)d_in[1];
  const float* fc_p_w = (const float*)d_in[2];
  const float* fc_p_b = (const float*)d_in[3];
  const float* fc_c_w = (const float*)d_in[4];
  const float* fc_c_b = (const float*)d_in[5];
  const float* fc0_w = (const float*)d_in[6];
  const float* fc0_b = (const float*)d_in[7];
  const float* fc1_w = (const float*)d_in[8];
  const float* fc1_b = (const float*)d_in[9];
  const float* fc_out_w = (const float*)d_in[10];
  const float* fc_out_b = (const float*)d_in[11];
  float* out = (float*)d_out;
  _Float16* ws = (_Float16*)d_ws;

  const int nq = in_sizes[1] / 3;

  convert_weights<<<(WS_HALVES + 255) / 256, 256, 0, stream>>>(fc_p_w, fc_c_w,
                                                               fc0_w, fc1_w, ws);
  const int grid = (nq + TQ - 1) / TQ;
  patch_decoder_kernel<<<grid, BLOCK, 0, stream>>>(z_feats, query, ws, fc_p_b,
                                                   fc_c_b, fc0_b, fc1_b, fc_out_w,
                                                   fc_out_b, out, nq);
}